// Round 1
// baseline (151.937 us; speedup 1.0000x reference)
//
#include <hip/hip_runtime.h>

// Problem dims (AdditiveAttention_56865366999388)
#define NB 4
#define NQL 512   // query length
#define ML 512    // key/value length
#define DDIM 256  // DQ == DK == DV
#define HDIM 256  // H

static constexpr float TWO_LOG2E = 2.8853900817779268f; // 2*log2(e)
static constexpr float LOG2E     = 1.4426950408889634f;

// ---------------------------------------------------------------------------
// Kernel 1: projection + exp.
//   EqT[b][h][l] = exp2( TWO_LOG2E * sum_d src[b][l][d]*W[d][h] )  (= e^{2q})
//   Stored h-major so scores kernel reads contiguous l rows.
// 64l x 64h tile, 4l x 4h per thread (16 out), 256 thr.
// grid: (l_tiles=8, h_tiles=4, z=8: z>>2 which, z&3 b) = 256 blocks (1/CU).
// LDS per K-step: 8 x ds_read_b128 per 64 FMA (was 2 per 8) -> ~10us model.
// ---------------------------------------------------------------------------
__global__ __launch_bounds__(256) void proj_kernel(
    const float* __restrict__ q_src, const float* __restrict__ k_src,
    const float* __restrict__ Wq,    const float* __restrict__ Wk,
    float* __restrict__ EqT,         float* __restrict__ EkT)
{
    const int z = blockIdx.z;
    const int b = z & 3;
    const int which = z >> 2;
    const float* __restrict__ src  = which ? k_src : q_src;
    const float* __restrict__ W    = which ? Wk    : Wq;
    float* __restrict__       outT = which ? EkT   : EqT;

    const int l0 = blockIdx.x * 64;
    const int h0 = blockIdx.y * 64;
    const int t  = threadIdx.x;
    const int tx = t & 15;   // h group (4 each)
    const int ty = t >> 4;   // l group (4 each)

    __shared__ float sX[64][36];   // [ll][dd] 64 l x 32 d (+pad)
    __shared__ float sW[32][68];   // [dd][hh] 32 d x 64 h (+pad)

    const int rA = t >> 2, cgA = t & 3;   // X stage: 64 rows x 4 grps(8 d)
    const int rB = t >> 3, cgB = t & 7;   // W stage: 32 rows x 8 grps(8 h)

    float acc[4][4];
    #pragma unroll
    for (int i = 0; i < 4; i++)
        #pragma unroll
        for (int j = 0; j < 4; j++) acc[i][j] = 0.f;

    // reg-prefetch for d0 = 0
    const float* xp0 = &src[(size_t)(b * NQL + l0 + rA) * DDIM + cgA * 8];
    float4 xa = ((const float4*)xp0)[0];
    float4 xb = ((const float4*)xp0)[1];
    const float* wp0 = &W[(size_t)rB * HDIM + h0 + cgB * 8];
    float4 wa = ((const float4*)wp0)[0];
    float4 wb = ((const float4*)wp0)[1];

    for (int d0 = 0; d0 < DDIM; d0 += 32) {
        __syncthreads();
        *(float4*)&sX[rA][cgA * 8]     = xa;
        *(float4*)&sX[rA][cgA * 8 + 4] = xb;
        *(float4*)&sW[rB][cgB * 8]     = wa;
        *(float4*)&sW[rB][cgB * 8 + 4] = wb;
        __syncthreads();
        if (d0 + 32 < DDIM) {  // issue next-step loads; they overlap compute
            const float* xp = &src[(size_t)(b * NQL + l0 + rA) * DDIM + (d0 + 32) + cgA * 8];
            xa = ((const float4*)xp)[0];
            xb = ((const float4*)xp)[1];
            const float* wp = &W[(size_t)(d0 + 32 + rB) * HDIM + h0 + cgB * 8];
            wa = ((const float4*)wp)[0];
            wb = ((const float4*)wp)[1];
        }
        #pragma unroll
        for (int dc = 0; dc < 8; dc++) {
            float4 w0 = *(const float4*)&sW[dc * 4 + 0][tx * 4];
            float4 w1 = *(const float4*)&sW[dc * 4 + 1][tx * 4];
            float4 w2 = *(const float4*)&sW[dc * 4 + 2][tx * 4];
            float4 w3 = *(const float4*)&sW[dc * 4 + 3][tx * 4];
            #pragma unroll
            for (int i = 0; i < 4; i++) {
                float4 x = *(const float4*)&sX[ty * 4 + i][dc * 4];
                acc[i][0] = fmaf(x.x, w0.x, acc[i][0]);
                acc[i][1] = fmaf(x.x, w0.y, acc[i][1]);
                acc[i][2] = fmaf(x.x, w0.z, acc[i][2]);
                acc[i][3] = fmaf(x.x, w0.w, acc[i][3]);
                acc[i][0] = fmaf(x.y, w1.x, acc[i][0]);
                acc[i][1] = fmaf(x.y, w1.y, acc[i][1]);
                acc[i][2] = fmaf(x.y, w1.z, acc[i][2]);
                acc[i][3] = fmaf(x.y, w1.w, acc[i][3]);
                acc[i][0] = fmaf(x.z, w2.x, acc[i][0]);
                acc[i][1] = fmaf(x.z, w2.y, acc[i][1]);
                acc[i][2] = fmaf(x.z, w2.z, acc[i][2]);
                acc[i][3] = fmaf(x.z, w2.w, acc[i][3]);
                acc[i][0] = fmaf(x.w, w3.x, acc[i][0]);
                acc[i][1] = fmaf(x.w, w3.y, acc[i][1]);
                acc[i][2] = fmaf(x.w, w3.z, acc[i][2]);
                acc[i][3] = fmaf(x.w, w3.w, acc[i][3]);
            }
        }
    }

    #pragma unroll
    for (int j = 0; j < 4; j++) {
        float4 o;   // 4 l-values for one h column -> contiguous in EqT
        o.x = __builtin_amdgcn_exp2f(acc[0][j] * TWO_LOG2E);
        o.y = __builtin_amdgcn_exp2f(acc[1][j] * TWO_LOG2E);
        o.z = __builtin_amdgcn_exp2f(acc[2][j] * TWO_LOG2E);
        o.w = __builtin_amdgcn_exp2f(acc[3][j] * TWO_LOG2E);
        *(float4*)&outT[(size_t)(b * HDIM + h0 + tx * 4 + j) * NQL + l0 + ty * 4] = o;
    }
}

// ---------------------------------------------------------------------------
// Kernel 2: scores + exp + partial row sums (softmax kernel eliminated).
//   tanh(q+k) = 1 - 2/(e^{2q}e^{2k}+1);  S = sum_h Wv[h] - sum_h 2*Wv[h]/a,
//   a = fma(Eq,Ek,1).  Paired reciprocal: rcp(a0*a1) then unpair via mul.
//   |S| <= sum|Wv| ~ 13, so exp(S) needs no max subtraction in fp32.
//   Writes P = exp(S); per-block partial row sums -> Spart[mt][b][n].
// 64n x 64m tile, 4x4 per thread, 256 thr, grid (8,8,4) = 256 blocks (1/CU).
// ---------------------------------------------------------------------------
__global__ __launch_bounds__(256) void scores_kernel(
    const float* __restrict__ EqT, const float* __restrict__ EkT,
    const float* __restrict__ Wv, float* __restrict__ S,
    float* __restrict__ Spart)
{
    const int b  = blockIdx.z;
    const int mt = blockIdx.x;
    const int m0 = mt * 64;
    const int n0 = blockIdx.y * 64;
    const int t  = threadIdx.x;
    const int tx = t & 15;   // m group (4 each)
    const int ty = t >> 4;   // n group (4 each)

    __shared__ float sQ[32][68];   // [hh][nn]
    __shared__ float sK[32][68];   // [hh][mm]
    __shared__ float sWV[32];

    const int rS = t >> 3, cgS = t & 7;  // staging: 32 h rows x 8 grps(8)

    float acc[4][4];
    #pragma unroll
    for (int i = 0; i < 4; i++)
        #pragma unroll
        for (int j = 0; j < 4; j++) acc[i][j] = 0.f;
    float swv = 0.f;

    // reg-prefetch h0 = 0
    const float* qp0 = &EqT[(size_t)(b * HDIM + rS) * NQL + n0 + cgS * 8];
    float4 qa = ((const float4*)qp0)[0];
    float4 qb = ((const float4*)qp0)[1];
    const float* kp0 = &EkT[(size_t)(b * HDIM + rS) * ML + m0 + cgS * 8];
    float4 ka = ((const float4*)kp0)[0];
    float4 kb = ((const float4*)kp0)[1];
    float wvp = (t < 32) ? Wv[t] : 0.f;

    for (int h0 = 0; h0 < HDIM; h0 += 32) {
        __syncthreads();
        *(float4*)&sQ[rS][cgS * 8]     = qa;
        *(float4*)&sQ[rS][cgS * 8 + 4] = qb;
        *(float4*)&sK[rS][cgS * 8]     = ka;
        *(float4*)&sK[rS][cgS * 8 + 4] = kb;
        if (t < 32) sWV[t] = wvp;
        __syncthreads();
        if (h0 + 32 < HDIM) {
            const float* qp = &EqT[(size_t)(b * HDIM + h0 + 32 + rS) * NQL + n0 + cgS * 8];
            qa = ((const float4*)qp)[0];
            qb = ((const float4*)qp)[1];
            const float* kp = &EkT[(size_t)(b * HDIM + h0 + 32 + rS) * ML + m0 + cgS * 8];
            ka = ((const float4*)kp)[0];
            kb = ((const float4*)kp)[1];
            if (t < 32) wvp = Wv[h0 + 32 + t];
        }
        #pragma unroll
        for (int hh = 0; hh < 32; hh++) {
            float4 q4 = *(const float4*)&sQ[hh][ty * 4];
            float4 k4 = *(const float4*)&sK[hh][tx * 4];
            float wv = sWV[hh];
            swv += wv;
            const float nw2 = -2.0f * wv;
            float qv[4] = {q4.x, q4.y, q4.z, q4.w};
            #pragma unroll
            for (int i = 0; i < 4; i++) {
                float a0 = fmaf(qv[i], k4.x, 1.0f);   // e^{2(q+k)} + 1
                float a1 = fmaf(qv[i], k4.y, 1.0f);
                float a2 = fmaf(qv[i], k4.z, 1.0f);
                float a3 = fmaf(qv[i], k4.w, 1.0f);
                float r01 = __builtin_amdgcn_rcpf(a0 * a1);
                float r23 = __builtin_amdgcn_rcpf(a2 * a3);
                acc[i][0] = fmaf(nw2, r01 * a1, acc[i][0]);
                acc[i][1] = fmaf(nw2, r01 * a0, acc[i][1]);
                acc[i][2] = fmaf(nw2, r23 * a3, acc[i][2]);
                acc[i][3] = fmaf(nw2, r23 * a2, acc[i][3]);
            }
        }
    }

    // epilogue: P = exp(S) unnormalized (safe: |S| <= ~13), + partial row sums
    float rs[4];
    #pragma unroll
    for (int i = 0; i < 4; i++) {
        float4 p;
        p.x = __builtin_amdgcn_exp2f((swv + acc[i][0]) * LOG2E);
        p.y = __builtin_amdgcn_exp2f((swv + acc[i][1]) * LOG2E);
        p.z = __builtin_amdgcn_exp2f((swv + acc[i][2]) * LOG2E);
        p.w = __builtin_amdgcn_exp2f((swv + acc[i][3]) * LOG2E);
        *(float4*)&S[(size_t)(b * NQL + n0 + ty * 4 + i) * ML + m0 + tx * 4] = p;
        rs[i] = (p.x + p.y) + (p.z + p.w);
    }
    #pragma unroll
    for (int off = 1; off < 16; off <<= 1) {
        #pragma unroll
        for (int i = 0; i < 4; i++) rs[i] += __shfl_xor(rs[i], off);
    }
    if ((t & 15) == 0) {
        #pragma unroll
        for (int i = 0; i < 4; i++)
            Spart[(size_t)(mt * NB + b) * NQL + n0 + ty * 4 + i] = rs[i];
    }
}

// ---------------------------------------------------------------------------
// Kernel 4: out[b][n][v] = (sum_m P[b][n][m] * V[b][m][v]) / rowsum[b][n]
// 16n x 64v tile, 4n x 4v per thread, m-split across the block's 2 waves,
// 128 thr, grid (4, 32, 4) = 512 blocks (2/CU).
// A (=P) read direct from global (4 distinct 16B addrs/wave, L2-hot,
// broadcast-coalesced); V via LDS; normalization fused.
// ---------------------------------------------------------------------------
__global__ __launch_bounds__(128) void av_kernel(
    const float* __restrict__ P, const float* __restrict__ Spart,
    const float* __restrict__ V, float* __restrict__ O)
{
    const int b  = blockIdx.z;
    const int v0 = blockIdx.x * 64;
    const int n0 = blockIdx.y * 16;
    const int t  = threadIdx.x;
    const int lane = t & 63;
    const int wid  = t >> 6;      // m-half selector (2 waves)
    const int tx = lane & 15;     // v group (4 each)
    const int tn = lane >> 4;     // n group (4 rows each)

    __shared__ float sV[64][68];  // [mm][vv] 64 m x 64 v (+pad)
    __shared__ float sInv[16];

    if (t < 16) {  // softmax denominators from scores partials
        float s = 0.f;
        #pragma unroll
        for (int mt = 0; mt < 8; mt++)
            s += Spart[(size_t)(mt * NB + b) * NQL + n0 + t];
        sInv[t] = 1.0f / s;
    }

    float acc[4][4];
    #pragma unroll
    for (int i = 0; i < 4; i++)
        #pragma unroll
        for (int j = 0; j < 4; j++) acc[i][j] = 0.f;

    const int rV = t >> 1, cgV = t & 1;   // V stage: 64 rows x 2 grps(32)
    float4 p[8];
    #pragma unroll
    for (int k = 0; k < 8; k++)
        p[k] = *(const float4*)&V[(size_t)(b * ML + rV) * DDIM + v0 + cgV * 32 + k * 4];

    for (int m0 = 0; m0 < ML; m0 += 64) {
        __syncthreads();
        #pragma unroll
        for (int k = 0; k < 8; k++)
            *(float4*)&sV[rV][cgV * 32 + k * 4] = p[k];
        __syncthreads();
        if (m0 + 64 < ML) {
            #pragma unroll
            for (int k = 0; k < 8; k++)
                p[k] = *(const float4*)&V[(size_t)(b * ML + m0 + 64 + rV) * DDIM + v0 + cgV * 32 + k * 4];
        }
        const int mb = wid * 32;
        #pragma unroll
        for (int mg = 0; mg < 8; mg++) {
            float4 a0 = *(const float4*)&P[(size_t)(b * NQL + n0 + tn * 4 + 0) * ML + m0 + mb + mg * 4];
            float4 a1 = *(const float4*)&P[(size_t)(b * NQL + n0 + tn * 4 + 1) * ML + m0 + mb + mg * 4];
            float4 a2 = *(const float4*)&P[(size_t)(b * NQL + n0 + tn * 4 + 2) * ML + m0 + mb + mg * 4];
            float4 a3 = *(const float4*)&P[(size_t)(b * NQL + n0 + tn * 4 + 3) * ML + m0 + mb + mg * 4];
            float4 v0v = *(const float4*)&sV[mb + mg * 4 + 0][tx * 4];
            float4 v1v = *(const float4*)&sV[mb + mg * 4 + 1][tx * 4];
            float4 v2v = *(const float4*)&sV[mb + mg * 4 + 2][tx * 4];
            float4 v3v = *(const float4*)&sV[mb + mg * 4 + 3][tx * 4];
#define AV_ROW(i, a)                                                         \
            acc[i][0] = fmaf(a.x, v0v.x, acc[i][0]);                         \
            acc[i][1] = fmaf(a.x, v0v.y, acc[i][1]);                         \
            acc[i][2] = fmaf(a.x, v0v.z, acc[i][2]);                         \
            acc[i][3] = fmaf(a.x, v0v.w, acc[i][3]);                         \
            acc[i][0] = fmaf(a.y, v1v.x, acc[i][0]);                         \
            acc[i][1] = fmaf(a.y, v1v.y, acc[i][1]);                         \
            acc[i][2] = fmaf(a.y, v1v.z, acc[i][2]);                         \
            acc[i][3] = fmaf(a.y, v1v.w, acc[i][3]);                         \
            acc[i][0] = fmaf(a.z, v2v.x, acc[i][0]);                         \
            acc[i][1] = fmaf(a.z, v2v.y, acc[i][1]);                         \
            acc[i][2] = fmaf(a.z, v2v.z, acc[i][2]);                         \
            acc[i][3] = fmaf(a.z, v2v.w, acc[i][3]);                         \
            acc[i][0] = fmaf(a.w, v3v.x, acc[i][0]);                         \
            acc[i][1] = fmaf(a.w, v3v.y, acc[i][1]);                         \
            acc[i][2] = fmaf(a.w, v3v.z, acc[i][2]);                         \
            acc[i][3] = fmaf(a.w, v3v.w, acc[i][3]);
            AV_ROW(0, a0)
            AV_ROW(1, a1)
            AV_ROW(2, a2)
            AV_ROW(3, a3)
#undef AV_ROW
        }
    }

    // cross-wave m-half reduction (sRed aliases sV: safe after barrier)
    __syncthreads();
    float* sRed = &sV[0][0];
    if (wid == 1) {
        #pragma unroll
        for (int i = 0; i < 4; i++) {
            float4 r = {acc[i][0], acc[i][1], acc[i][2], acc[i][3]};
            *(float4*)&sRed[(tn * 4 + i) * 64 + tx * 4] = r;
        }
    }
    __syncthreads();
    if (wid == 0) {
        #pragma unroll
        for (int i = 0; i < 4; i++) {
            float4 r = *(const float4*)&sRed[(tn * 4 + i) * 64 + tx * 4];
            float inv = sInv[tn * 4 + i];
            float4 o;
            o.x = (acc[i][0] + r.x) * inv;
            o.y = (acc[i][1] + r.y) * inv;
            o.z = (acc[i][2] + r.z) * inv;
            o.w = (acc[i][3] + r.w) * inv;
            *(float4*)&O[(size_t)(b * NQL + n0 + tn * 4 + i) * DDIM + v0 + tx * 4] = o;
        }
    }
}

// ---------------------------------------------------------------------------
extern "C" void kernel_launch(void* const* d_in, const int* in_sizes, int n_in,
                              void* d_out, int out_size, void* d_ws, size_t ws_size,
                              hipStream_t stream)
{
    const float* query = (const float*)d_in[0]; // (4,512,256)
    const float* key   = (const float*)d_in[1]; // (4,512,256)
    const float* value = (const float*)d_in[2]; // (4,512,256)
    const float* Wq    = (const float*)d_in[3]; // (256,256)
    const float* Wk    = (const float*)d_in[4]; // (256,256)
    const float* Wv    = (const float*)d_in[5]; // (256,)
    float* out = (float*)d_out;                 // (4,512,256)

    // workspace layout (fp32): EqT 2MB | EkT 2MB | P 4MB | Spart 64KB
    float* EqT   = (float*)d_ws;                      // [4][256][512]
    float* EkT   = EqT + (size_t)NB * HDIM * NQL;     // [4][256][512]
    float* S     = EkT + (size_t)NB * HDIM * ML;      // [4][512][512] (P = exp(S))
    float* Spart = S + (size_t)NB * NQL * ML;         // [8][4][512] partial row sums

    dim3 gProj(NQL / 64, HDIM / 64, NB * 2);
    proj_kernel<<<gProj, 256, 0, stream>>>(query, key, Wq, Wk, EqT, EkT);

    dim3 gSc(ML / 64, NQL / 64, NB);
    scores_kernel<<<gSc, 256, 0, stream>>>(EqT, EkT, Wv, S, Spart);

    dim3 gAv(DDIM / 64, NQL / 16, NB);
    av_kernel<<<gAv, 128, 0, stream>>>(S, Spart, value, out);
}

// Round 2
// 146.824 us; speedup vs baseline: 1.0348x; 1.0348x over previous
//
#include <hip/hip_runtime.h>

// Problem dims (AdditiveAttention_56865366999388)
#define NB 4
#define NQL 512   // query length
#define ML 512    // key/value length
#define DDIM 256  // DQ == DK == DV
#define HDIM 256  // H

static constexpr float TWO_LOG2E = 2.8853900817779268f; // 2*log2(e)
static constexpr float LOG2E     = 1.4426950408889634f;

// ---------------------------------------------------------------------------
// Kernel 1: projection + exp. NO LDS — W rows are L2-hot (256KB shared),
// X streams with L1 line reuse. 64l x 64h tile, 512 thr, 2l x 4h per thread.
// grid 256 (1D): idx = ((lt + 8*ht)<<3) | (which<<2) | b
//   -> idx&7 pins (which,b) per XCD: each XCD reads one src tensor slice.
// 8 waves/CU = 2/SIMD; no barriers -> latency hidden by ILP + TLP.
// ---------------------------------------------------------------------------
__global__ __launch_bounds__(512) void proj_kernel(
    const float* __restrict__ q_src, const float* __restrict__ k_src,
    const float* __restrict__ Wq,    const float* __restrict__ Wk,
    float* __restrict__ EqT,         float* __restrict__ EkT)
{
    const int idx   = blockIdx.x;
    const int b     = idx & 3;
    const int which = (idx >> 2) & 1;
    const int lt    = (idx >> 3) & 7;
    const int ht    = idx >> 6;
    const float* __restrict__ src = which ? k_src : q_src;
    const float* __restrict__ W   = which ? Wk : Wq;
    float* __restrict__ outT      = which ? EkT : EqT;

    const int l0 = lt * 64, h0 = ht * 64;
    const int t  = threadIdx.x;
    const int tx = t & 15;   // h group (4 each)
    const int ty = t >> 4;   // l group (2 each), 0..31

    const float* xp0 = &src[(size_t)(b * NQL + l0 + ty * 2) * DDIM];
    const float* xp1 = xp0 + DDIM;
    const float* wp  = &W[h0 + tx * 4];

    float acc[2][4] = {{0.f, 0.f, 0.f, 0.f}, {0.f, 0.f, 0.f, 0.f}};

    #pragma unroll 4
    for (int dc = 0; dc < 64; ++dc) {
        float4 xa = *(const float4*)(xp0 + dc * 4);
        float4 xb = *(const float4*)(xp1 + dc * 4);
        const float* wrow = wp + (size_t)dc * 4 * HDIM;
        float4 w0 = *(const float4*)(wrow);
        float4 w1 = *(const float4*)(wrow + HDIM);
        float4 w2 = *(const float4*)(wrow + 2 * HDIM);
        float4 w3 = *(const float4*)(wrow + 3 * HDIM);
#define PJ(xv, wv)                                                   \
        acc[0][0] = fmaf(xa.xv, wv.x, acc[0][0]);                    \
        acc[0][1] = fmaf(xa.xv, wv.y, acc[0][1]);                    \
        acc[0][2] = fmaf(xa.xv, wv.z, acc[0][2]);                    \
        acc[0][3] = fmaf(xa.xv, wv.w, acc[0][3]);                    \
        acc[1][0] = fmaf(xb.xv, wv.x, acc[1][0]);                    \
        acc[1][1] = fmaf(xb.xv, wv.y, acc[1][1]);                    \
        acc[1][2] = fmaf(xb.xv, wv.z, acc[1][2]);                    \
        acc[1][3] = fmaf(xb.xv, wv.w, acc[1][3]);
        PJ(x, w0) PJ(y, w1) PJ(z, w2) PJ(w, w3)
#undef PJ
    }

    #pragma unroll
    for (int j = 0; j < 4; ++j) {
        float2 o;   // e^{2*proj}, stored h-major: [b][h][l]
        o.x = __builtin_amdgcn_exp2f(acc[0][j] * TWO_LOG2E);
        o.y = __builtin_amdgcn_exp2f(acc[1][j] * TWO_LOG2E);
        *(float2*)&outT[(size_t)(b * HDIM + h0 + tx * 4 + j) * NQL + l0 + ty * 2] = o;
    }
}

// ---------------------------------------------------------------------------
// Kernel 2: scores + exp + partial row sums. NO LDS.
//   tanh(q+k) = 1 - 2/(e^{2q}e^{2k}+1);  S = sum_h Wv[h] - sum_h 2*Wv[h]/a,
//   a = fma(Eq,Ek,1). Paired rcp. P = exp(S) unnormalized (|S| <= ~13).
// q: b64 broadcast (2 addrs/wave); k: b128 coalesced 512B/wave; Wv: s_load.
// 32n x 128m tile, 512 thr, 2n x 4m per thread.
// grid 256 (1D): idx = b | mt<<2 | nt<<4 -> idx&7 pins (b, m-parity)/XCD:
// working set Eq[b] 512KB + half Ek[b] 256KB, L2-resident.
// ---------------------------------------------------------------------------
__global__ __launch_bounds__(512) void scores_kernel(
    const float* __restrict__ EqT, const float* __restrict__ EkT,
    const float* __restrict__ Wv, float* __restrict__ P,
    float* __restrict__ Spart)
{
    const int idx = blockIdx.x;
    const int b   = idx & 3;
    const int mt  = (idx >> 2) & 3;
    const int nt  = idx >> 4;          // 0..15
    const int m0  = mt * 128, n0 = nt * 32;
    const int t   = threadIdx.x;
    const int tx  = t & 31;   // m group (4 each)
    const int ty  = t >> 5;   // n group (2 each), 0..15

    const float* qp = &EqT[(size_t)b * HDIM * NQL + n0 + ty * 2];
    const float* kp = &EkT[(size_t)b * HDIM * ML + m0 + tx * 4];

    float acc0[4] = {0.f, 0.f, 0.f, 0.f};
    float acc1[4] = {0.f, 0.f, 0.f, 0.f};
    float swv = 0.f;

    #pragma unroll 4
    for (int hh = 0; hh < HDIM; ++hh) {
        float2 q2 = *(const float2*)(qp + (size_t)hh * NQL);
        float4 k4 = *(const float4*)(kp + (size_t)hh * ML);
        const float wv = Wv[hh];           // uniform -> scalar load
        swv += wv;
        const float nw2 = -2.0f * wv;
        {   // n-row 0
            float a0 = fmaf(q2.x, k4.x, 1.0f);
            float a1 = fmaf(q2.x, k4.y, 1.0f);
            float a2 = fmaf(q2.x, k4.z, 1.0f);
            float a3 = fmaf(q2.x, k4.w, 1.0f);
            float r01 = __builtin_amdgcn_rcpf(a0 * a1);
            float r23 = __builtin_amdgcn_rcpf(a2 * a3);
            acc0[0] = fmaf(nw2, r01 * a1, acc0[0]);
            acc0[1] = fmaf(nw2, r01 * a0, acc0[1]);
            acc0[2] = fmaf(nw2, r23 * a3, acc0[2]);
            acc0[3] = fmaf(nw2, r23 * a2, acc0[3]);
        }
        {   // n-row 1
            float a0 = fmaf(q2.y, k4.x, 1.0f);
            float a1 = fmaf(q2.y, k4.y, 1.0f);
            float a2 = fmaf(q2.y, k4.z, 1.0f);
            float a3 = fmaf(q2.y, k4.w, 1.0f);
            float r01 = __builtin_amdgcn_rcpf(a0 * a1);
            float r23 = __builtin_amdgcn_rcpf(a2 * a3);
            acc1[0] = fmaf(nw2, r01 * a1, acc1[0]);
            acc1[1] = fmaf(nw2, r01 * a0, acc1[1]);
            acc1[2] = fmaf(nw2, r23 * a3, acc1[2]);
            acc1[3] = fmaf(nw2, r23 * a2, acc1[3]);
        }
    }

    // epilogue: P = exp(S), partial row sums over this block's 128 m.
    float rs[2];
    {
        float4 p;
        p.x = __builtin_amdgcn_exp2f((swv + acc0[0]) * LOG2E);
        p.y = __builtin_amdgcn_exp2f((swv + acc0[1]) * LOG2E);
        p.z = __builtin_amdgcn_exp2f((swv + acc0[2]) * LOG2E);
        p.w = __builtin_amdgcn_exp2f((swv + acc0[3]) * LOG2E);
        *(float4*)&P[(size_t)(b * NQL + n0 + ty * 2 + 0) * ML + m0 + tx * 4] = p;
        rs[0] = (p.x + p.y) + (p.z + p.w);
    }
    {
        float4 p;
        p.x = __builtin_amdgcn_exp2f((swv + acc1[0]) * LOG2E);
        p.y = __builtin_amdgcn_exp2f((swv + acc1[1]) * LOG2E);
        p.z = __builtin_amdgcn_exp2f((swv + acc1[2]) * LOG2E);
        p.w = __builtin_amdgcn_exp2f((swv + acc1[3]) * LOG2E);
        *(float4*)&P[(size_t)(b * NQL + n0 + ty * 2 + 1) * ML + m0 + tx * 4] = p;
        rs[1] = (p.x + p.y) + (p.z + p.w);
    }
    // reduce across tx (lane bits 0..4 only -> stays within n-row group)
    #pragma unroll
    for (int off = 1; off < 32; off <<= 1) {
        rs[0] += __shfl_xor(rs[0], off);
        rs[1] += __shfl_xor(rs[1], off);
    }
    if (tx == 0) {
        float2 o = {rs[0], rs[1]};
        *(float2*)&Spart[(size_t)(mt * NB + b) * NQL + n0 + ty * 2] = o;
    }
}

// ---------------------------------------------------------------------------
// Kernel 3: out[b][n][v] = (sum_m P[b][n][m] * V[b][m][v]) / rowsum[b][n]
// NO LDS for operands: P broadcast (4 addrs/wave b128), V coalesced b128.
// 16n x 64v tile, m-split 4 across the block's 4 waves (128 m each),
// 256 thr, per-thread 4n x 4v. LDS only for 3->1 epilogue reduce.
// grid 512 (1D): idx = b | vt<<2 | nt<<4  (2 blocks/CU, 8 waves/CU).
// ---------------------------------------------------------------------------
__global__ __launch_bounds__(256) void av_kernel(
    const float* __restrict__ P, const float* __restrict__ Spart,
    const float* __restrict__ V, float* __restrict__ O)
{
    const int idx = blockIdx.x;
    const int b   = idx & 3;
    const int vt  = (idx >> 2) & 3;
    const int nt  = idx >> 4;          // 0..31
    const int v0  = vt * 64, n0 = nt * 16;
    const int t    = threadIdx.x;
    const int lane = t & 63;
    const int wid  = t >> 6;    // m-quarter selector (4 waves)
    const int tx   = lane & 15; // v group (4 each)
    const int tn   = lane >> 4; // n group (4 rows each)

    __shared__ float sInv[16];
    __shared__ float sRed[3][16][64];   // 12 KB epilogue reduce

    if (t < 16) {   // softmax denominators from scores partials (wave 0)
        float s = 0.f;
        #pragma unroll
        for (int mt = 0; mt < 4; ++mt)
            s += Spart[(size_t)(mt * NB + b) * NQL + n0 + t];
        sInv[t] = 1.0f / s;
    }

    float acc[4][4] = {};
    const int mbase = wid * 128;
    const float* pbase = &P[(size_t)(b * NQL + n0 + tn * 4) * ML + mbase];
    const float* vbase = &V[(size_t)(b * ML + mbase) * DDIM + v0 + tx * 4];

    #pragma unroll 2
    for (int mc = 0; mc < 32; ++mc) {
        const float* pp = pbase + mc * 4;
        float4 a0 = *(const float4*)(pp);
        float4 a1 = *(const float4*)(pp + ML);
        float4 a2 = *(const float4*)(pp + 2 * ML);
        float4 a3 = *(const float4*)(pp + 3 * ML);
        const float* vv = vbase + (size_t)mc * 4 * DDIM;
        float4 vr0 = *(const float4*)(vv);
        float4 vr1 = *(const float4*)(vv + DDIM);
        float4 vr2 = *(const float4*)(vv + 2 * DDIM);
        float4 vr3 = *(const float4*)(vv + 3 * DDIM);
#define AVR(i, a)                                                    \
        acc[i][0] = fmaf(a.x, vr0.x, acc[i][0]);                     \
        acc[i][1] = fmaf(a.x, vr0.y, acc[i][1]);                     \
        acc[i][2] = fmaf(a.x, vr0.z, acc[i][2]);                     \
        acc[i][3] = fmaf(a.x, vr0.w, acc[i][3]);                     \
        acc[i][0] = fmaf(a.y, vr1.x, acc[i][0]);                     \
        acc[i][1] = fmaf(a.y, vr1.y, acc[i][1]);                     \
        acc[i][2] = fmaf(a.y, vr1.z, acc[i][2]);                     \
        acc[i][3] = fmaf(a.y, vr1.w, acc[i][3]);                     \
        acc[i][0] = fmaf(a.z, vr2.x, acc[i][0]);                     \
        acc[i][1] = fmaf(a.z, vr2.y, acc[i][1]);                     \
        acc[i][2] = fmaf(a.z, vr2.z, acc[i][2]);                     \
        acc[i][3] = fmaf(a.z, vr2.w, acc[i][3]);                     \
        acc[i][0] = fmaf(a.w, vr3.x, acc[i][0]);                     \
        acc[i][1] = fmaf(a.w, vr3.y, acc[i][1]);                     \
        acc[i][2] = fmaf(a.w, vr3.z, acc[i][2]);                     \
        acc[i][3] = fmaf(a.w, vr3.w, acc[i][3]);
        AVR(0, a0) AVR(1, a1) AVR(2, a2) AVR(3, a3)
#undef AVR
    }

    __syncthreads();
    if (wid != 0) {
        #pragma unroll
        for (int i = 0; i < 4; ++i) {
            float4 r = {acc[i][0], acc[i][1], acc[i][2], acc[i][3]};
            *(float4*)&sRed[wid - 1][tn * 4 + i][tx * 4] = r;
        }
    }
    __syncthreads();
    if (wid == 0) {
        #pragma unroll
        for (int i = 0; i < 4; ++i) {
            float4 r1 = *(const float4*)&sRed[0][tn * 4 + i][tx * 4];
            float4 r2 = *(const float4*)&sRed[1][tn * 4 + i][tx * 4];
            float4 r3 = *(const float4*)&sRed[2][tn * 4 + i][tx * 4];
            const float inv = sInv[tn * 4 + i];
            float4 o;
            o.x = (acc[i][0] + r1.x + r2.x + r3.x) * inv;
            o.y = (acc[i][1] + r1.y + r2.y + r3.y) * inv;
            o.z = (acc[i][2] + r1.z + r2.z + r3.z) * inv;
            o.w = (acc[i][3] + r1.w + r2.w + r3.w) * inv;
            *(float4*)&O[(size_t)(b * NQL + n0 + tn * 4 + i) * DDIM + v0 + tx * 4] = o;
        }
    }
}

// ---------------------------------------------------------------------------
extern "C" void kernel_launch(void* const* d_in, const int* in_sizes, int n_in,
                              void* d_out, int out_size, void* d_ws, size_t ws_size,
                              hipStream_t stream)
{
    const float* query = (const float*)d_in[0]; // (4,512,256)
    const float* key   = (const float*)d_in[1]; // (4,512,256)
    const float* value = (const float*)d_in[2]; // (4,512,256)
    const float* Wq    = (const float*)d_in[3]; // (256,256)
    const float* Wk    = (const float*)d_in[4]; // (256,256)
    const float* Wv    = (const float*)d_in[5]; // (256,)
    float* out = (float*)d_out;                 // (4,512,256)

    // workspace layout (fp32): EqT 2MB | EkT 2MB | P 4MB | Spart 32KB
    float* EqT   = (float*)d_ws;                      // [4][256][512]
    float* EkT   = EqT + (size_t)NB * HDIM * NQL;     // [4][256][512]
    float* P     = EkT + (size_t)NB * HDIM * ML;      // [4][512][512] (= exp(S))
    float* Spart = P + (size_t)NB * NQL * ML;         // [4][4][512] partial row sums

    proj_kernel<<<dim3(256), 512, 0, stream>>>(query, key, Wq, Wk, EqT, EkT);
    scores_kernel<<<dim3(256), 512, 0, stream>>>(EqT, EkT, Wv, P, Spart);
    av_kernel<<<dim3(512), 256, 0, stream>>>(P, Spart, value, out);
}